// Round 20
// baseline (217.509 us; speedup 1.0000x reference)
//
#include <hip/hip_runtime.h>
#include <cstdint>
#include <cstddef>

typedef _Float16 f16;
typedef _Float16 f16x4 __attribute__((ext_vector_type(4)));
typedef _Float16 f16x8 __attribute__((ext_vector_type(8)));
typedef float    f32x4 __attribute__((ext_vector_type(4)));

#define NB 64
#define NN 262144   // 512*512

__device__ __forceinline__ void gload_lds16(const void* g, void* l) {
    __builtin_amdgcn_global_load_lds(
        (const __attribute__((address_space(1))) void*)g,
        (__attribute__((address_space(3))) void*)l, 16, 0, 0);
}

// LDS transpose-tile column swizzle: stride 64 floats, group = (col/4) ^ (row/4).
__device__ __forceinline__ int SWC(int row, int col) {
    return ((((col >> 2) ^ (row >> 2)) & 15) << 2) | (col & 3);
}

// pre1: streaming-only prep. 2048 blocks grid-striding 9408 units:
//  u < 8192        : cvtX 2048-float convert
//  u in [8192,8384): transW 64x64 tile (x64)
//  u >= 8384       : colsum partial (16 adj rows, f32x4 cols) -> part[b][32][512]
__global__ __launch_bounds__(256)
void k_pre1(const float* __restrict__ adj, float* __restrict__ part,
            const float* __restrict__ W1, const float* __restrict__ W2,
            const float* __restrict__ W3, f16* __restrict__ Wt,
            const float* __restrict__ X0, f16* __restrict__ Xa) {
    __shared__ __align__(16) float t[4096];
    const int tid = threadIdx.x;

    for (int u = blockIdx.x; u < 9408; u += 2048) {
        if (u < 8192) {
            size_t i = ((size_t)u * 256 + tid) * 8;
            float4 v0 = *(const float4*)(X0 + i);
            float4 v1 = *(const float4*)(X0 + i + 4);
            f16x8 o;
            o[0] = (f16)v0.x; o[1] = (f16)v0.y; o[2] = (f16)v0.z; o[3] = (f16)v0.w;
            o[4] = (f16)v1.x; o[5] = (f16)v1.y; o[6] = (f16)v1.z; o[7] = (f16)v1.w;
            *(f16x8*)(Xa + i) = o;
        } else if (u < 8384) {
            int cb = u - 8192;
            int z = cb >> 6, rem = cb & 63;
            const float* W = z == 0 ? W1 : (z == 1 ? W2 : W3);
            f16* out = Wt + (size_t)z * NN;
            int k0 = (rem >> 3) * 64, d0 = (rem & 7) * 64;
            int c = tid & 63, r4 = tid >> 6;
            #pragma unroll
            for (int s = 0; s < 16; ++s) {
                int rr = r4 + s * 4;
                t[rr * 64 + SWC(rr, c)] = W[(size_t)(k0 + rr) * 512 + d0 + c];
            }
            __syncthreads();
            int kq = (tid & 15) * 4;
            int db = tid >> 4;
            #pragma unroll
            for (int s = 0; s < 4; ++s) {
                int dd = db + s * 16;
                f16x4 o;
                #pragma unroll
                for (int q = 0; q < 4; ++q)
                    o[q] = (f16)(64.f * t[(kq + q) * 64 + SWC(kq + q, dd)]);
                *(f16x4*)&out[(size_t)(d0 + dd) * 512 + k0 + kq] = o;
            }
            __syncthreads();
        } else {
            // colsum partial: part[b][ch][n] = sum of 16 rows of adj[b][:, n]
            int cu = u - 8384;                    // 0..1023
            int b = cu >> 4;
            int rr0 = (cu & 15) * 32 + (tid >> 7) * 16;
            int c4 = (tid & 127) * 4;
            const float* ab = adj + (size_t)b * NN + (size_t)rr0 * 512 + c4;
            f32x4 s = {0.f, 0.f, 0.f, 0.f};
            #pragma unroll
            for (int i = 0; i < 16; ++i)
                s += *(const f32x4*)(ab + (size_t)i * 512);
            int ch2 = (cu & 15) * 2 + (tid >> 7);
            *(f32x4*)&part[((size_t)b * 32 + ch2) * 512 + c4] = s;
        }
    }
}

// Mixed-role dispatch: G1 (R13 128^2 gemm, RM) + adj-transpose, co-resident 2/CU.
// bid%5==0 -> gemm block (1024); else -> transpose unit (4096). No intra deps:
// transpose output (A_raw) is read only by G2 (next dispatch).
__global__ __launch_bounds__(256, 2)
void k_g1t(const float* __restrict__ adj, f16* __restrict__ A_raw,
           const f16* __restrict__ Xa, const f16* __restrict__ Wt1,
           f16* __restrict__ S_t, const float* __restrict__ part) {
    __shared__ __align__(16) f16 Plds[2][8192];
    __shared__ __align__(16) f16 Qlds[2][8192];
    __shared__ float rs_lds[128];
    const int bid = blockIdx.x, tid = threadIdx.x;
    const int q = bid / 5, r5 = bid % 5;

    if (r5 != 0) {
        // ---- transpose role: A_raw[b][i][j] = f16(adj[b][j][i]) ----
        const int tix = 4 * q + r5 - 1;            // 0..4095
        const int xcd = tix & 7, loc = tix >> 3;
        const int b = xcd * 8 + (loc >> 6);
        const int tile = loc & 63;
        const int i0 = (tile >> 3) * 64, j0 = (tile & 7) * 64;
        const float* ab = adj + (size_t)b * NN;
        float* t = (float*)&Plds[0][0];            // 16 KiB alias
        #pragma unroll
        for (int s = 0; s < 4; ++s) {
            int rr = s * 16 + (tid >> 4);
            int creal = SWC(rr, (tid & 15) * 4);
            gload_lds16(&ab[(size_t)(j0 + rr) * 512 + i0 + creal],
                        &t[s * 1024 + tid * 4]);
        }
        asm volatile("s_waitcnt vmcnt(0)" ::: "memory");
        __syncthreads();
        f16* Ab = A_raw + (size_t)b * NN;
        int jq = (tid & 15) * 4;
        int ib = tid >> 4;
        #pragma unroll
        for (int s = 0; s < 4; ++s) {
            int ii = ib + s * 16;
            f16x4 o;
            #pragma unroll
            for (int qq = 0; qq < 4; ++qq)
                o[qq] = (f16)t[(jq + qq) * 64 + SWC(jq + qq, ii)];
            *(f16x4*)&Ab[(size_t)(i0 + ii) * 512 + j0 + jq] = o;
        }
        return;
    }

    // ---- G1 gemm role (R13 gemm_tn_ct, RM=true): S_t = 4*r[m]*acc ----
    const int gid  = q;                            // 0..1023
    const int lane = tid & 63;
    const int wid  = tid >> 6;
    const int wm   = wid >> 1;
    const int wn   = wid & 1;
    const int swz = (gid & 7) * 128 + (gid >> 3);
    const int b   = swz >> 4;
    const int tt  = swz & 15;
    const int m0  = (tt >> 2) * 128;
    const int n0  = (tt & 3) * 128;

    const f16* Pb = Xa + (size_t)b * NN;
    const f16* Qb = Wt1;

    const int srow = tid >> 3;
    const int sswz = (tid & 7) ^ (srow & 7);
    const int fr = lane & 15, fs = lane >> 4, fx = fr & 7;

    auto stage = [&](const f16* __restrict__ Gb, int row0, f16* lds, int k0) {
        #pragma unroll
        for (int r = 0; r < 4; ++r) {
            const f16* src = Gb + (size_t)(row0 + r * 32 + srow) * 512 + k0 + sswz * 8;
            gload_lds16(src, lds + r * 2048 + tid * 8);
        }
    };

    f32x4 acc[4][4] = {};
    stage(Pb, m0, &Plds[0][0], 0);
    stage(Qb, n0, &Qlds[0][0], 0);

    if (tid < 128) {
        const float* p = part + (size_t)b * 16384 + m0 + tid;
        float s = 0.f;
        #pragma unroll
        for (int ch = 0; ch < 32; ++ch) s += p[ch * 512];
        rs_lds[tid] = (s > 0.f) ? rsqrtf(s) : 0.f;
    }

    for (int t = 0; t < 8; ++t) {
        const int nb = t & 1;
        if (t < 7) {
            stage(Pb, m0, &Plds[nb ^ 1][0], (t + 1) * 64);
            stage(Qb, n0, &Qlds[nb ^ 1][0], (t + 1) * 64);
            asm volatile("s_waitcnt vmcnt(8)" ::: "memory");
        } else {
            asm volatile("s_waitcnt vmcnt(0)" ::: "memory");
        }
        __builtin_amdgcn_s_barrier();

        const f16* Pl = &Plds[nb][0];
        const f16* Ql = &Qlds[nb][0];
        #pragma unroll
        for (int krep = 0; krep < 2; ++krep) {
            const int sp = ((fs + krep * 4) ^ fx) * 8;
            f16x8 af[4], bf[4];
            #pragma unroll
            for (int mi = 0; mi < 4; ++mi)
                af[mi] = *(const f16x8*)&Pl[(wm * 64 + mi * 16 + fr) * 64 + sp];
            #pragma unroll
            for (int ni = 0; ni < 4; ++ni)
                bf[ni] = *(const f16x8*)&Ql[(wn * 64 + ni * 16 + fr) * 64 + sp];
            __builtin_amdgcn_s_setprio(1);
            #pragma unroll
            for (int mi = 0; mi < 4; ++mi)
                #pragma unroll
                for (int ni = 0; ni < 4; ++ni)
                    acc[mi][ni] = __builtin_amdgcn_mfma_f32_16x16x32_f16(
                        af[mi], bf[ni], acc[mi][ni], 0, 0, 0);
            __builtin_amdgcn_s_setprio(0);
        }
        asm volatile("s_waitcnt lgkmcnt(0)" ::: "memory");
        __builtin_amdgcn_sched_barrier(0);
        __builtin_amdgcn_s_barrier();
    }

    const int cmb = (lane >> 4) * 4;
    f32x4 rm4[4];
    #pragma unroll
    for (int mi = 0; mi < 4; ++mi)
        rm4[mi] = *(const f32x4*)&rs_lds[wm * 64 + mi * 16 + cmb];
    #pragma unroll
    for (int mi = 0; mi < 4; ++mi) {
        #pragma unroll
        for (int ni = 0; ni < 4; ++ni) {
            const int n = n0 + wn * 64 + ni * 16 + fr;
            const int m = m0 + wm * 64 + mi * 16 + cmb;
            f16x4 o;
            #pragma unroll
            for (int qq = 0; qq < 4; ++qq)
                o[qq] = (f16)(acc[mi][ni][qq] * 4.f * rm4[mi][qq]);
            *(f16x4*)&S_t[(size_t)b * NN + (size_t)n * 512 + m] = o;
        }
    }
}

// ---------------- 8-phase 256^2 GEMM (R17 structure; part = 32 chunks) ----------------
template<bool BIAS, bool RELU, bool OUTF32, bool RM, bool RN>
__global__ __launch_bounds__(512, 1)
void gemm8(const f16* __restrict__ P, size_t pstr,
           const f16* __restrict__ Qt, size_t qstr,
           void* __restrict__ Cout, size_t cstr,
           const float* __restrict__ bias, const float* __restrict__ part,
           float iscale, float oscale) {
    __shared__ __align__(16) f16 Albuf[2][16384];
    __shared__ __align__(16) f16 Blbuf[2][16384];
    __shared__ float rs_lds[256];

    const int tid  = threadIdx.x;
    const int lane = tid & 63;
    const int wid  = tid >> 6;
    const int wm   = wid >> 2;
    const int wn   = wid & 3;

    const int wg  = blockIdx.x;
    const int swz = (wg & 7) * 32 + (wg >> 3);
    const int b   = swz >> 2;
    const int tt  = swz & 3;
    const int m0  = (tt >> 1) * 256;
    const int n0  = (tt & 1) * 256;

    const f16* Pb = P + (size_t)b * pstr;
    const f16* Qb = Qt + (size_t)b * qstr;

    const int fr = lane & 15, fs = lane >> 4, fx = fr & 7;

    if ((RM || RN) && tid < 256) {
        const float* p = part + (size_t)b * 16384 + (RM ? m0 : n0) + tid;
        float s = 0.f;
        #pragma unroll
        for (int ch = 0; ch < 32; ++ch) s += p[ch * 512];
        rs_lds[tid] = (s > 0.f) ? rsqrtf(s) : 0.f;
    }
    asm volatile("s_waitcnt vmcnt(0)" ::: "memory");

    auto stage_half = [&](const f16* __restrict__ Gb, int row0g, f16* buf, int h, int k0) {
        {
            int row = tid >> 3, sl = tid & 7;
            gload_lds16(Gb + (size_t)(row0g + h * 128 + row) * 512 + k0 + ((sl ^ (row & 7)) * 8),
                        buf + h * 8192 + tid * 8);
        }
        {
            int u = tid + 512;
            int row = u >> 3, sl = u & 7;
            gload_lds16(Gb + (size_t)(row0g + h * 128 + row) * 512 + k0 + ((sl ^ (row & 7)) * 8),
                        buf + h * 8192 + u * 8);
        }
    };

    f32x4 acc[8][4] = {};
    f16x8 af[4][2], bf[2][2];

    stage_half(Qb, n0, &Blbuf[0][0], 0, 0);
    stage_half(Qb, n0, &Blbuf[0][0], 1, 0);
    stage_half(Pb, m0, &Albuf[0][0], 0, 0);
    stage_half(Pb, m0, &Albuf[0][0], 1, 0);

#define LOAD_AF(QM)                                                            \
    _Pragma("unroll") for (int i = 0; i < 4; ++i) {                            \
        int row = wm * 128 + ((QM) * 4 + i) * 16 + fr;                         \
        _Pragma("unroll") for (int k = 0; k < 2; ++k)                          \
            af[i][k] = *(const f16x8*)&Al[row * 64 + ((fs + 4 * k) ^ fx) * 8]; \
    }
#define LOAD_BF(QN)                                                            \
    _Pragma("unroll") for (int j = 0; j < 2; ++j) {                            \
        int row = wn * 64 + ((QN) * 2 + j) * 16 + fr;                          \
        _Pragma("unroll") for (int k = 0; k < 2; ++k)                          \
            bf[j][k] = *(const f16x8*)&Bl[row * 64 + ((fs + 4 * k) ^ fx) * 8]; \
    }
#define PH_SYNC()                                                              \
    __builtin_amdgcn_s_barrier();                                              \
    asm volatile("s_waitcnt lgkmcnt(0)" ::: "memory");                         \
    __builtin_amdgcn_sched_barrier(0);
#define DO_MFMA(QM, QN)                                                        \
    __builtin_amdgcn_s_setprio(1);                                             \
    _Pragma("unroll") for (int i = 0; i < 4; ++i)                              \
        _Pragma("unroll") for (int j = 0; j < 2; ++j)                          \
            _Pragma("unroll") for (int k = 0; k < 2; ++k)                      \
                acc[(QM) * 4 + i][(QN) * 2 + j] =                              \
                    __builtin_amdgcn_mfma_f32_16x16x32_f16(                    \
                        af[i][k], bf[j][k], acc[(QM) * 4 + i][(QN) * 2 + j],   \
                        0, 0, 0);                                              \
    __builtin_amdgcn_s_setprio(0);                                             \
    __builtin_amdgcn_s_barrier();

    for (int t = 0; t < 8; ++t) {
        f16* Al = &Albuf[t & 1][0];
        f16* Bl = &Blbuf[t & 1][0];
        f16* An = &Albuf[(t & 1) ^ 1][0];
        f16* Bn = &Blbuf[(t & 1) ^ 1][0];
        const int kn = (t + 1) * 64;

        asm volatile("s_waitcnt vmcnt(0)" ::: "memory");
        __builtin_amdgcn_s_barrier();

        LOAD_AF(0) LOAD_BF(0)
        if (t < 7) stage_half(Qb, n0, Bn, 0, kn);
        PH_SYNC(); DO_MFMA(0, 0)
        LOAD_BF(1)
        if (t < 7) stage_half(Qb, n0, Bn, 1, kn);
        PH_SYNC(); DO_MFMA(0, 1)
        LOAD_AF(1)
        if (t < 7) stage_half(Pb, m0, An, 0, kn);
        PH_SYNC(); DO_MFMA(1, 1)
        LOAD_BF(0)
        if (t < 7) stage_half(Pb, m0, An, 1, kn);
        PH_SYNC(); DO_MFMA(1, 0)
    }
#undef LOAD_AF
#undef LOAD_BF
#undef PH_SYNC
#undef DO_MFMA

    const int cmb = (lane >> 4) * 4;
    f32x4 rm4[8];
    float rn1[4];
    if (RM) {
        #pragma unroll
        for (int mi = 0; mi < 8; ++mi)
            rm4[mi] = *(const f32x4*)&rs_lds[wm * 128 + mi * 16 + cmb];
    }
    if (RN) {
        #pragma unroll
        for (int ni = 0; ni < 4; ++ni)
            rn1[ni] = rs_lds[wn * 64 + ni * 16 + fr];
    }
    #pragma unroll
    for (int mi = 0; mi < 8; ++mi) {
        #pragma unroll
        for (int ni = 0; ni < 4; ++ni) {
            const int n = n0 + wn * 64 + ni * 16 + fr;
            const int m = m0 + wm * 128 + mi * 16 + cmb;
            float v[4];
            #pragma unroll
            for (int qq = 0; qq < 4; ++qq) {
                float x = acc[mi][ni][qq] * iscale;
                if (RM) x *= rm4[mi][qq];
                if (RN) x *= rn1[ni];
                if (BIAS) x += bias[m + qq];
                if (RELU) x = fmaxf(x, 0.f);
                v[qq] = x * oscale;
            }
            if (OUTF32) {
                float* Cb = (float*)Cout + (size_t)b * cstr;
                f32x4 o; o[0] = v[0]; o[1] = v[1]; o[2] = v[2]; o[3] = v[3];
                *(f32x4*)&Cb[(size_t)n * 512 + m] = o;
            } else {
                f16* Cb = (f16*)Cout + (size_t)b * cstr;
                f16x4 o; o[0] = (f16)v[0]; o[1] = (f16)v[1]; o[2] = (f16)v[2]; o[3] = (f16)v[3];
                *(f16x4*)&Cb[(size_t)n * 512 + m] = o;
            }
        }
    }
}

extern "C" void kernel_launch(void* const* d_in, const int* in_sizes, int n_in,
                              void* d_out, int out_size, void* d_ws, size_t ws_size,
                              hipStream_t stream) {
    const float* X0  = (const float*)d_in[0];
    const float* adj = (const float*)d_in[1];
    const float* W1  = (const float*)d_in[2];
    const float* b1  = (const float*)d_in[3];
    const float* W2  = (const float*)d_in[4];
    const float* b2  = (const float*)d_in[5];
    const float* W3  = (const float*)d_in[6];
    const float* b3  = (const float*)d_in[7];

    uint8_t* ws = (uint8_t*)d_ws;
    float* part = (float*)ws;                                 // 64*32*512*4 = 4 MiB
    f16* Wt1 = (f16*)(ws + (4 << 20));                        // 3 x 512 KiB
    f16* A_raw = (f16*)(ws + (4 << 20) + (size_t)3 * NN * 2); // 32 MiB (adj^T f16)
    f16* Xa  = A_raw + (size_t)NB * NN;                       // 32 MiB
    f16* S_t = Xa + (size_t)NB * NN;                          // 32 MiB

    k_pre1<<<dim3(2048), dim3(256), 0, stream>>>(adj, part, W1, W2, W3, Wt1, X0, Xa);
    // G1 (reads Xa, Wt1, part) runs alongside the adj-transpose (writes A_raw for G2)
    k_g1t <<<dim3(5120), dim3(256), 0, stream>>>(adj, A_raw, Xa, Wt1, S_t, part);

    dim3 gg(256), gb(512);
    // ledger: Xa holds 256^l * X_l; Wt = 64*W; S' = c_l * r_j * S_l (c1=256, c2=c3=262144).
    gemm8<true,  true,  false, false, true ><<<gg, gb, 0, stream>>>(S_t, (size_t)NN, A_raw, (size_t)NN, Xa, (size_t)NN, b1, part, 1.f / 256.f, 256.f);
    gemm8<false, false, false, true,  false><<<gg, gb, 0, stream>>>(Xa,  (size_t)NN, Wt1 + NN, (size_t)0,  S_t, (size_t)NN, nullptr, part, 16.f, 1.f);
    gemm8<true,  true,  false, false, true ><<<gg, gb, 0, stream>>>(S_t, (size_t)NN, A_raw, (size_t)NN, Xa, (size_t)NN, b2, part, 1.f / 262144.f, 256.f);
    gemm8<false, false, false, true,  false><<<gg, gb, 0, stream>>>(Xa,  (size_t)NN, Wt1 + 2 * NN, (size_t)0,  S_t, (size_t)NN, nullptr, part, 16.f, 1.f);
    gemm8<true,  false, true,  false, true ><<<gg, gb, 0, stream>>>(S_t, (size_t)NN, A_raw, (size_t)NN, d_out, (size_t)NN, b3, part, 1.f / 262144.f, 1.f);
}

// Round 21
// 200.745 us; speedup vs baseline: 1.0835x; 1.0835x over previous
//
#include <hip/hip_runtime.h>
#include <cstdint>
#include <cstddef>

typedef _Float16 f16;
typedef _Float16 f16x4 __attribute__((ext_vector_type(4)));
typedef _Float16 f16x8 __attribute__((ext_vector_type(8)));
typedef float    f32x4 __attribute__((ext_vector_type(4)));

#define NB 64
#define NN 262144   // 512*512

__device__ __forceinline__ void gload_lds16(const void* g, void* l) {
    __builtin_amdgcn_global_load_lds(
        (const __attribute__((address_space(1))) void*)g,
        (__attribute__((address_space(3))) void*)l, 16, 0, 0);
}

// LDS transpose-tile column swizzle: stride 64 floats, group = (col/4) ^ (row/4).
__device__ __forceinline__ int SWC(int row, int col) {
    return ((((col >> 2) ^ (row >> 2)) & 15) << 2) | (col & 3);
}

// prep: interleaved roles (R17 record config).
//   bid<8192 even -> adj 64x64 transpose tile + colsum partial (gload_lds, SWC)
//   bid<8192 odd  -> cvtX unit ;  [8192,12288) -> cvtX ;  [12288,12480) -> transW
__global__ __launch_bounds__(256)
void k_prep(const float* __restrict__ adj, f16* __restrict__ A_raw,
            float* __restrict__ part,
            const float* __restrict__ W1, const float* __restrict__ W2,
            const float* __restrict__ W3, f16* __restrict__ Wt,
            const float* __restrict__ X0, f16* __restrict__ Xa) {
    __shared__ __align__(16) float t[4096];
    __shared__ float red[4][64];
    const int bid = blockIdx.x, tid = threadIdx.x;

    bool do_cvt = false;
    int cvt_idx = 0;
    if (bid < 8192) {
        if (bid & 1) { do_cvt = true; cvt_idx = bid >> 1; }
    } else if (bid < 12288) {
        do_cvt = true; cvt_idx = 4096 + (bid - 8192);
    }

    if (do_cvt) {
        size_t i = ((size_t)cvt_idx * 256 + tid) * 8;
        float4 v0 = *(const float4*)(X0 + i);
        float4 v1 = *(const float4*)(X0 + i + 4);
        f16x8 o;
        o[0] = (f16)v0.x; o[1] = (f16)v0.y; o[2] = (f16)v0.z; o[3] = (f16)v0.w;
        o[4] = (f16)v1.x; o[5] = (f16)v1.y; o[6] = (f16)v1.z; o[7] = (f16)v1.w;
        *(f16x8*)(Xa + i) = o;
    } else if (bid < 8192) {
        const int idx = bid >> 1;
        const int xcd = idx & 7, loc = idx >> 3;
        const int b = xcd * 8 + (loc >> 6);
        const int tile = loc & 63;
        const int i0 = (tile >> 3) * 64, j0 = (tile & 7) * 64;
        const int jt = tile & 7;
        const float* ab = adj + (size_t)b * NN;
        #pragma unroll
        for (int s = 0; s < 4; ++s) {
            int rr = s * 16 + (tid >> 4);
            int creal = SWC(rr, (tid & 15) * 4);
            gload_lds16(&ab[(size_t)(j0 + rr) * 512 + i0 + creal],
                        &t[s * 1024 + tid * 4]);
        }
        asm volatile("s_waitcnt vmcnt(0)" ::: "memory");
        __syncthreads();
        {
            int c = tid & 63, g = tid >> 6;
            float sg = 0.f;
            #pragma unroll
            for (int s = 0; s < 16; ++s) {
                int row = g * 16 + s;
                sg += t[row * 64 + SWC(row, c)];
            }
            red[g][c] = sg;
        }
        f16* Ab = A_raw + (size_t)b * NN;
        int jq = (tid & 15) * 4;
        int ib = tid >> 4;
        #pragma unroll
        for (int s = 0; s < 4; ++s) {
            int ii = ib + s * 16;
            f16x4 o;
            #pragma unroll
            for (int q = 0; q < 4; ++q)
                o[q] = (f16)t[(jq + q) * 64 + SWC(jq + q, ii)];
            *(f16x4*)&Ab[(size_t)(i0 + ii) * 512 + j0 + jq] = o;
        }
        __syncthreads();
        if (tid < 64)
            part[((size_t)b * 8 + jt) * 512 + i0 + tid] =
                red[0][tid] + red[1][tid] + red[2][tid] + red[3][tid];
    } else {
        int cb = bid - 12288;
        int z = cb >> 6, rem = cb & 63;
        const float* W = z == 0 ? W1 : (z == 1 ? W2 : W3);
        f16* out = Wt + (size_t)z * NN;
        int k0 = (rem >> 3) * 64, d0 = (rem & 7) * 64;
        int c = tid & 63, r4 = tid >> 6;
        #pragma unroll
        for (int s = 0; s < 16; ++s) {
            int rr = r4 + s * 4;
            t[rr * 64 + SWC(rr, c)] = W[(size_t)(k0 + rr) * 512 + d0 + c];
        }
        __syncthreads();
        int kq = (tid & 15) * 4;
        int db = tid >> 4;
        #pragma unroll
        for (int s = 0; s < 4; ++s) {
            int dd = db + s * 16;
            f16x4 o;
            #pragma unroll
            for (int q = 0; q < 4; ++q)
                o[q] = (f16)(64.f * t[(kq + q) * 64 + SWC(kq + q, dd)]);
            *(f16x4*)&out[(size_t)(d0 + dd) * 512 + k0 + kq] = o;
        }
    }
}

// ---------------- 8-phase 256^2 GEMM (R17 record config) ----------------
template<bool BIAS, bool RELU, bool OUTF32, bool RM, bool RN>
__global__ __launch_bounds__(512, 1)
void gemm8(const f16* __restrict__ P, size_t pstr,
           const f16* __restrict__ Qt, size_t qstr,
           void* __restrict__ Cout, size_t cstr,
           const float* __restrict__ bias, const float* __restrict__ part,
           float iscale, float oscale) {
    __shared__ __align__(16) f16 Albuf[2][16384];
    __shared__ __align__(16) f16 Blbuf[2][16384];
    __shared__ float rs_lds[256];

    const int tid  = threadIdx.x;
    const int lane = tid & 63;
    const int wid  = tid >> 6;
    const int wm   = wid >> 2;
    const int wn   = wid & 3;

    const int wg  = blockIdx.x;
    const int swz = (wg & 7) * 32 + (wg >> 3);
    const int b   = swz >> 2;
    const int tt  = swz & 3;
    const int m0  = (tt >> 1) * 256;
    const int n0  = (tt & 1) * 256;

    const f16* Pb = P + (size_t)b * pstr;
    const f16* Qb = Qt + (size_t)b * qstr;

    const int fr = lane & 15, fs = lane >> 4, fx = fr & 7;

    if ((RM || RN) && tid < 256) {
        const float* p = part + (size_t)b * 4096 + (RM ? m0 : n0) + tid;
        float s = 0.f;
        #pragma unroll
        for (int jt = 0; jt < 8; ++jt) s += p[jt * 512];
        rs_lds[tid] = (s > 0.f) ? rsqrtf(s) : 0.f;
    }
    asm volatile("s_waitcnt vmcnt(0)" ::: "memory");

    auto stage_half = [&](const f16* __restrict__ Gb, int row0g, f16* buf, int h, int k0) {
        {
            int row = tid >> 3, sl = tid & 7;
            gload_lds16(Gb + (size_t)(row0g + h * 128 + row) * 512 + k0 + ((sl ^ (row & 7)) * 8),
                        buf + h * 8192 + tid * 8);
        }
        {
            int u = tid + 512;
            int row = u >> 3, sl = u & 7;
            gload_lds16(Gb + (size_t)(row0g + h * 128 + row) * 512 + k0 + ((sl ^ (row & 7)) * 8),
                        buf + h * 8192 + u * 8);
        }
    };

    f32x4 acc[8][4] = {};
    f16x8 af[4][2], bf[2][2];

    stage_half(Qb, n0, &Blbuf[0][0], 0, 0);
    stage_half(Qb, n0, &Blbuf[0][0], 1, 0);
    stage_half(Pb, m0, &Albuf[0][0], 0, 0);
    stage_half(Pb, m0, &Albuf[0][0], 1, 0);

#define LOAD_AF(QM)                                                            \
    _Pragma("unroll") for (int i = 0; i < 4; ++i) {                            \
        int row = wm * 128 + ((QM) * 4 + i) * 16 + fr;                         \
        _Pragma("unroll") for (int k = 0; k < 2; ++k)                          \
            af[i][k] = *(const f16x8*)&Al[row * 64 + ((fs + 4 * k) ^ fx) * 8]; \
    }
#define LOAD_BF(QN)                                                            \
    _Pragma("unroll") for (int j = 0; j < 2; ++j) {                            \
        int row = wn * 64 + ((QN) * 2 + j) * 16 + fr;                          \
        _Pragma("unroll") for (int k = 0; k < 2; ++k)                          \
            bf[j][k] = *(const f16x8*)&Bl[row * 64 + ((fs + 4 * k) ^ fx) * 8]; \
    }
#define PH_SYNC()                                                              \
    __builtin_amdgcn_s_barrier();                                              \
    asm volatile("s_waitcnt lgkmcnt(0)" ::: "memory");                         \
    __builtin_amdgcn_sched_barrier(0);
#define DO_MFMA(QM, QN)                                                        \
    __builtin_amdgcn_s_setprio(1);                                             \
    _Pragma("unroll") for (int i = 0; i < 4; ++i)                              \
        _Pragma("unroll") for (int j = 0; j < 2; ++j)                          \
            _Pragma("unroll") for (int k = 0; k < 2; ++k)                      \
                acc[(QM) * 4 + i][(QN) * 2 + j] =                              \
                    __builtin_amdgcn_mfma_f32_16x16x32_f16(                    \
                        af[i][k], bf[j][k], acc[(QM) * 4 + i][(QN) * 2 + j],   \
                        0, 0, 0);                                              \
    __builtin_amdgcn_s_setprio(0);                                             \
    __builtin_amdgcn_s_barrier();

    for (int t = 0; t < 8; ++t) {
        f16* Al = &Albuf[t & 1][0];
        f16* Bl = &Blbuf[t & 1][0];
        f16* An = &Albuf[(t & 1) ^ 1][0];
        f16* Bn = &Blbuf[(t & 1) ^ 1][0];
        const int kn = (t + 1) * 64;

        asm volatile("s_waitcnt vmcnt(0)" ::: "memory");
        __builtin_amdgcn_s_barrier();

        LOAD_AF(0) LOAD_BF(0)
        if (t < 7) stage_half(Qb, n0, Bn, 0, kn);
        PH_SYNC(); DO_MFMA(0, 0)
        LOAD_BF(1)
        if (t < 7) stage_half(Qb, n0, Bn, 1, kn);
        PH_SYNC(); DO_MFMA(0, 1)
        LOAD_AF(1)
        if (t < 7) stage_half(Pb, m0, An, 0, kn);
        PH_SYNC(); DO_MFMA(1, 1)
        LOAD_BF(0)
        if (t < 7) stage_half(Pb, m0, An, 1, kn);
        PH_SYNC(); DO_MFMA(1, 0)
    }
#undef LOAD_AF
#undef LOAD_BF
#undef PH_SYNC
#undef DO_MFMA

    const int cmb = (lane >> 4) * 4;
    f32x4 rm4[8];
    float rn1[4];
    if (RM) {
        #pragma unroll
        for (int mi = 0; mi < 8; ++mi)
            rm4[mi] = *(const f32x4*)&rs_lds[wm * 128 + mi * 16 + cmb];
    }
    if (RN) {
        #pragma unroll
        for (int ni = 0; ni < 4; ++ni)
            rn1[ni] = rs_lds[wn * 64 + ni * 16 + fr];
    }
    #pragma unroll
    for (int mi = 0; mi < 8; ++mi) {
        #pragma unroll
        for (int ni = 0; ni < 4; ++ni) {
            const int n = n0 + wn * 64 + ni * 16 + fr;
            const int m = m0 + wm * 128 + mi * 16 + cmb;
            float v[4];
            #pragma unroll
            for (int q = 0; q < 4; ++q) {
                float x = acc[mi][ni][q] * iscale;
                if (RM) x *= rm4[mi][q];
                if (RN) x *= rn1[ni];
                if (BIAS) x += bias[m + q];
                if (RELU) x = fmaxf(x, 0.f);
                v[q] = x * oscale;
            }
            if (OUTF32) {
                float* Cb = (float*)Cout + (size_t)b * cstr;
                f32x4 o; o[0] = v[0]; o[1] = v[1]; o[2] = v[2]; o[3] = v[3];
                *(f32x4*)&Cb[(size_t)n * 512 + m] = o;
            } else {
                f16* Cb = (f16*)Cout + (size_t)b * cstr;
                f16x4 o; o[0] = (f16)v[0]; o[1] = (f16)v[1]; o[2] = (f16)v[2]; o[3] = (f16)v[3];
                *(f16x4*)&Cb[(size_t)n * 512 + m] = o;
            }
        }
    }
}

extern "C" void kernel_launch(void* const* d_in, const int* in_sizes, int n_in,
                              void* d_out, int out_size, void* d_ws, size_t ws_size,
                              hipStream_t stream) {
    const float* X0  = (const float*)d_in[0];
    const float* adj = (const float*)d_in[1];
    const float* W1  = (const float*)d_in[2];
    const float* b1  = (const float*)d_in[3];
    const float* W2  = (const float*)d_in[4];
    const float* b2  = (const float*)d_in[5];
    const float* W3  = (const float*)d_in[6];
    const float* b3  = (const float*)d_in[7];

    uint8_t* ws = (uint8_t*)d_ws;
    float* part = (float*)ws;                                 // 1 MiB
    f16* Wt1 = (f16*)(ws + (1 << 20));                        // 3 x 512 KiB
    f16* A_raw = (f16*)(ws + (1 << 20) + (size_t)3 * NN * 2); // 32 MiB (adj^T f16)
    f16* Xa  = A_raw + (size_t)NB * NN;                       // 32 MiB (X / activations)
    f16* S_t = Xa + (size_t)NB * NN;                          // 32 MiB

    k_prep<<<dim3(12480), dim3(256), 0, stream>>>(adj, A_raw, part, W1, W2, W3, Wt1, X0, Xa);

    dim3 gg(256), gb(512);
    // ledger: Xa holds 256^l * X_l; Wt = 64*W; S' = c_l * r_j * S_l (c1=256, c2=c3=262144).
    gemm8<false, false, false, true,  false><<<gg, gb, 0, stream>>>(Xa,  (size_t)NN, Wt1, (size_t)0,  S_t, (size_t)NN, nullptr, part, 4.f, 1.f);
    gemm8<true,  true,  false, false, true ><<<gg, gb, 0, stream>>>(S_t, (size_t)NN, A_raw, (size_t)NN, Xa, (size_t)NN, b1, part, 1.f / 256.f, 256.f);
    gemm8<false, false, false, true,  false><<<gg, gb, 0, stream>>>(Xa,  (size_t)NN, Wt1 + NN, (size_t)0,  S_t, (size_t)NN, nullptr, part, 16.f, 1.f);
    gemm8<true,  true,  false, false, true ><<<gg, gb, 0, stream>>>(S_t, (size_t)NN, A_raw, (size_t)NN, Xa, (size_t)NN, b2, part, 1.f / 262144.f, 256.f);
    gemm8<false, false, false, true,  false><<<gg, gb, 0, stream>>>(Xa,  (size_t)NN, Wt1 + 2 * NN, (size_t)0,  S_t, (size_t)NN, nullptr, part, 16.f, 1.f);
    gemm8<true,  false, true,  false, true ><<<gg, gb, 0, stream>>>(S_t, (size_t)NN, A_raw, (size_t)NN, d_out, (size_t)NN, b3, part, 1.f / 262144.f, 1.f);
}